// Round 1
// baseline (73.198 us; speedup 1.0000x reference)
//
#include <hip/hip_runtime.h>

#define TT 4096
#define DD 64
#define NCH 64
#define CS 64   // TT / NCH

// ws layout (in floats)
#define Q_OFF   0
#define K_OFF   (TT*DD)                 // 262144
#define Z_OFF   (K_OFF + 4*TT*DD)       // 1310720
#define CSUM_OFF (Z_OFF + 8*TT*DD)      // 3407872  (+ 4*2*NCH*DD = 32768) ~13.8 MB total

// ---------------------------------------------------------------------------
// Kernel 1: the five MLPs (Q from x1; K_m from x_m), thread-per-row.
// h lives in a per-thread LDS column (runtime-indexable, conflict-free:
// lane t always touches addresses k*64+t -> bank t%32, 2 lanes/bank = free).
// Weights are wave-uniform -> scalar loads.
// ---------------------------------------------------------------------------
__global__ __launch_bounds__(64) void mlp_kernel(
    const float* __restrict__ x1, const float* __restrict__ x2,
    const float* __restrict__ x3, const float* __restrict__ x4,
    const float* __restrict__ Wq_w, const float* __restrict__ Wq_b,
    const float* __restrict__ Wk_w, const float* __restrict__ Wk_b,
    float* __restrict__ ws)
{
    const int q  = blockIdx.x >> 6;    // 0 = Q-mlp, 1..4 = K-mlp (m = q-1)
    const int br = blockIdx.x & 63;    // row block
    const int t  = threadIdx.x;

    const float* x; const float* W; const float* B; float* out;
    if (q == 0) { x = x1; W = Wq_w; B = Wq_b; out = ws + Q_OFF; }
    else {
        const int m = q - 1;
        x = (m == 0) ? x1 : (m == 1) ? x2 : (m == 2) ? x3 : x4;
        W = Wk_w + m * 3 * DD * DD;
        B = Wk_b + m * 3 * DD;
        out = ws + K_OFF + m * TT * DD;
    }
    const int r = br * 64 + t;

    __shared__ float h[DD * 64];

    #pragma unroll
    for (int k = 0; k < 16; ++k) {
        float4 v = *reinterpret_cast<const float4*>(x + r * DD + 4 * k);
        h[(4*k + 0) * 64 + t] = v.x;
        h[(4*k + 1) * 64 + t] = v.y;
        h[(4*k + 2) * 64 + t] = v.z;
        h[(4*k + 3) * 64 + t] = v.w;
    }

    float acc[DD];
    for (int L = 0; L < 3; ++L) {
        #pragma unroll
        for (int d = 0; d < DD; ++d) acc[d] = B[L * DD + d];
        const float* WL = W + L * DD * DD;
        for (int k = 0; k < DD; ++k) {
            const float hk = h[k * 64 + t];
            const float* wk = WL + k * DD;
            #pragma unroll
            for (int d = 0; d < DD; ++d) acc[d] += hk * wk[d];
        }
        if (L < 2) {
            #pragma unroll
            for (int d = 0; d < DD; ++d) {
                acc[d] = fmaxf(acc[d], 0.f);
                h[d * 64 + t] = acc[d];
            }
        }
    }

    #pragma unroll
    for (int j = 0; j < 16; ++j) {
        float4 v = make_float4(acc[4*j], acc[4*j+1], acc[4*j+2], acc[4*j+3]);
        *reinterpret_cast<float4*>(out + r * DD + 4 * j) = v;
    }
}

// ---------------------------------------------------------------------------
// Kernel 2: per-(m, chunk) partial sums  csum[m][c][ch][d] = sum_j K_j[d]*V_j[c]
// ---------------------------------------------------------------------------
__global__ __launch_bounds__(64) void chunksum_kernel(
    const float* __restrict__ x1, const float* __restrict__ x2,
    const float* __restrict__ x3, const float* __restrict__ x4,
    float* __restrict__ ws)
{
    const int m  = blockIdx.x >> 6;
    const int ch = blockIdx.x & 63;
    const int d  = threadIdx.x;
    const float* xm = (m == 0) ? x1 : (m == 1) ? x2 : (m == 2) ? x3 : x4;
    const float* K = ws + K_OFF + m * TT * DD;

    float s0 = 0.f, s1 = 0.f;
    #pragma unroll 4
    for (int j = ch * CS; j < ch * CS + CS; ++j) {
        const float kv = K[j * DD + d];
        s0 += kv * xm[j * DD + 0];
        s1 += kv * xm[j * DD + 1];
    }
    float* csum = ws + CSUM_OFF;
    csum[((m * 2 + 0) * NCH + ch) * DD + d] = s0;
    csum[((m * 2 + 1) * NCH + ch) * DD + d] = s1;
}

// ---------------------------------------------------------------------------
// Kernel 3: in-place exclusive scan of the 512 (m,c,d) chunk chains
// ---------------------------------------------------------------------------
__global__ __launch_bounds__(512) void scan_kernel(float* __restrict__ ws)
{
    const int t  = threadIdx.x;     // 0..511 = (m*2+c)*64 + d
    const int mc = t >> 6;
    const int d  = t & 63;
    float* csum = ws + CSUM_OFF;
    float run = 0.f;
    for (int ch = 0; ch < NCH; ++ch) {
        float* p = csum + (mc * NCH + ch) * DD + d;
        const float v = *p;
        *p = run;
        run += v;
    }
}

// ---------------------------------------------------------------------------
// Kernel 4: materialize inclusive prefix Z[m][c][j][d]
// ---------------------------------------------------------------------------
__global__ __launch_bounds__(64) void zfill_kernel(
    const float* __restrict__ x1, const float* __restrict__ x2,
    const float* __restrict__ x3, const float* __restrict__ x4,
    float* __restrict__ ws)
{
    const int m  = blockIdx.x >> 6;
    const int ch = blockIdx.x & 63;
    const int d  = threadIdx.x;
    const float* xm = (m == 0) ? x1 : (m == 1) ? x2 : (m == 2) ? x3 : x4;
    const float* K = ws + K_OFF + m * TT * DD;
    const float* csum = ws + CSUM_OFF;
    float* Z = ws + Z_OFF;

    float r0 = csum[((m * 2 + 0) * NCH + ch) * DD + d];
    float r1 = csum[((m * 2 + 1) * NCH + ch) * DD + d];
    #pragma unroll 4
    for (int j = ch * CS; j < ch * CS + CS; ++j) {
        const float kv = K[j * DD + d];
        r0 += kv * xm[j * DD + 0];
        r1 += kv * xm[j * DD + 1];
        Z[((m * 2 + 0) * TT + j) * DD + d] = r0;
        Z[((m * 2 + 1) * TT + j) * DD + d] = r1;
    }
}

// ---------------------------------------------------------------------------
// Kernel 5: wave-per-row output.  p = upper_bound(t2_m, t1_i); out = Q_i . Z[p-1]
// ---------------------------------------------------------------------------
__global__ __launch_bounds__(256) void gather_kernel(
    const float* __restrict__ x1, const float* __restrict__ x2,
    const float* __restrict__ x3, const float* __restrict__ x4,
    const float* __restrict__ ws, float* __restrict__ out)
{
    const int lane = threadIdx.x & 63;
    const int wid  = threadIdx.x >> 6;
    const int i = blockIdx.x * 4 + wid;

    const float* Q = ws + Q_OFF;
    const float* Z = ws + Z_OFF;

    const float t1i = x1[i * DD + (DD - 1)];
    const float qd  = Q[i * DD + lane];
    float a0 = 0.f, a1 = 0.f;

    #pragma unroll
    for (int m = 0; m < 4; ++m) {
        const float* xm = (m == 0) ? x1 : (m == 1) ? x2 : (m == 2) ? x3 : x4;
        int lo = 0, hi = TT;
        while (lo < hi) {                       // upper_bound on sorted t2
            const int mid = (lo + hi) >> 1;
            if (xm[mid * DD + (DD - 1)] <= t1i) lo = mid + 1; else hi = mid;
        }
        if (lo > 0) {
            const int p = lo - 1;
            a0 += qd * Z[((m * 2 + 0) * TT + p) * DD + lane];
            a1 += qd * Z[((m * 2 + 1) * TT + p) * DD + lane];
        }
    }

    #pragma unroll
    for (int off = 32; off > 0; off >>= 1) {
        a0 += __shfl_xor(a0, off);
        a1 += __shfl_xor(a1, off);
    }
    if (lane == 0) {
        out[i * 2 + 0] = a0;
        out[i * 2 + 1] = a1;
    }
}

extern "C" void kernel_launch(void* const* d_in, const int* in_sizes, int n_in,
                              void* d_out, int out_size, void* d_ws, size_t ws_size,
                              hipStream_t stream)
{
    const float* x1   = (const float*)d_in[0];
    const float* x2   = (const float*)d_in[1];
    const float* x3   = (const float*)d_in[2];
    const float* x4   = (const float*)d_in[3];
    const float* Wq_w = (const float*)d_in[4];
    const float* Wq_b = (const float*)d_in[5];
    const float* Wk_w = (const float*)d_in[6];
    const float* Wk_b = (const float*)d_in[7];
    float* out = (float*)d_out;
    float* ws  = (float*)d_ws;

    hipLaunchKernelGGL(mlp_kernel,      dim3(5 * 64), dim3(64),  0, stream,
                       x1, x2, x3, x4, Wq_w, Wq_b, Wk_w, Wk_b, ws);
    hipLaunchKernelGGL(chunksum_kernel, dim3(4 * NCH), dim3(64), 0, stream,
                       x1, x2, x3, x4, ws);
    hipLaunchKernelGGL(scan_kernel,     dim3(1), dim3(512), 0, stream, ws);
    hipLaunchKernelGGL(zfill_kernel,    dim3(4 * NCH), dim3(64), 0, stream,
                       x1, x2, x3, x4, ws);
    hipLaunchKernelGGL(gather_kernel,   dim3(TT / 4), dim3(256), 0, stream,
                       x1, x2, x3, x4, ws, out);
}

// Round 2
// 65.828 us; speedup vs baseline: 1.1120x; 1.1120x over previous
//
#include <hip/hip_runtime.h>

#define TT 4096
#define DD 64
#define NCH 64
#define CS 64   // TT / NCH

// ws layout (in floats)
#define Q_OFF   0
#define K_OFF   (TT*DD)                 // 262144
#define Z_OFF   (K_OFF + 4*TT*DD)       // 1310720
#define CSUM_OFF (Z_OFF + 8*TT*DD)      // 3407872  (+ 4*2*NCH*DD floats) ~13.8 MB total

// ---------------------------------------------------------------------------
// Kernel 1: the five MLPs (Q from x1; K_m from x_m).
// Block = 256 threads = 4 waves over a 64-row tile. lane = row, wave w owns
// output dims [16w, 16w+16). h kept transposed in LDS (h[k][row]) so every
// read h[k*64+lane] and write h[d*64+lane] is stride-1 across banks (free).
// Weight offsets are readfirstlane'd -> scalar loads on the SMEM pipe;
// k-loop unrolled x4 to keep several s_loads in flight. 1280 waves total.
// ---------------------------------------------------------------------------
__global__ __launch_bounds__(256) void mlp_kernel(
    const float* __restrict__ x1, const float* __restrict__ x2,
    const float* __restrict__ x3, const float* __restrict__ x4,
    const float* __restrict__ Wq_w, const float* __restrict__ Wq_b,
    const float* __restrict__ Wk_w, const float* __restrict__ Wk_b,
    float* __restrict__ ws)
{
    const int q    = blockIdx.x >> 6;    // 0 = Q-mlp, 1..4 = K-mlp (m = q-1)
    const int br   = blockIdx.x & 63;    // row block
    const int lane = threadIdx.x & 63;   // row within tile
    const int w    = threadIdx.x >> 6;   // dim-group 0..3

    const float* x; const float* W; const float* B; float* out;
    if (q == 0) { x = x1; W = Wq_w; B = Wq_b; out = ws + Q_OFF; }
    else {
        const int m = q - 1;
        x = (m == 0) ? x1 : (m == 1) ? x2 : (m == 2) ? x3 : x4;
        W = Wk_w + m * 3 * DD * DD;
        B = Wk_b + m * 3 * DD;
        out = ws + K_OFF + m * TT * DD;
    }
    const int gr = br * 64 + lane;

    // wave-uniform dim-group offset -> lets compiler use scalar loads for W/B
    const int dofs = __builtin_amdgcn_readfirstlane(16 * w);

    __shared__ float h[DD * 64];   // h[k][row], transposed

    // init h = x (each wave writes its 16 dims of its lane's row)
    {
        const float* xr = x + gr * DD + dofs;
        #pragma unroll
        for (int j4 = 0; j4 < 4; ++j4) {
            float4 v = *reinterpret_cast<const float4*>(xr + 4 * j4);
            h[(dofs + 4*j4 + 0) * 64 + lane] = v.x;
            h[(dofs + 4*j4 + 1) * 64 + lane] = v.y;
            h[(dofs + 4*j4 + 2) * 64 + lane] = v.z;
            h[(dofs + 4*j4 + 3) * 64 + lane] = v.w;
        }
    }

    float acc[16];
    for (int L = 0; L < 3; ++L) {
        __syncthreads();   // h for this layer fully written
        const float* WL = W + L * DD * DD + dofs;   // + k*DD + j
        const float* BL = B + L * DD + dofs;
        #pragma unroll
        for (int j = 0; j < 16; ++j) acc[j] = BL[j];

        #pragma unroll 4
        for (int k = 0; k < DD; ++k) {
            const float hk = h[k * 64 + lane];
            const float4 w0 = *reinterpret_cast<const float4*>(WL + k * DD + 0);
            const float4 w1 = *reinterpret_cast<const float4*>(WL + k * DD + 4);
            const float4 w2 = *reinterpret_cast<const float4*>(WL + k * DD + 8);
            const float4 w3 = *reinterpret_cast<const float4*>(WL + k * DD + 12);
            acc[ 0] += hk * w0.x;  acc[ 1] += hk * w0.y;
            acc[ 2] += hk * w0.z;  acc[ 3] += hk * w0.w;
            acc[ 4] += hk * w1.x;  acc[ 5] += hk * w1.y;
            acc[ 6] += hk * w1.z;  acc[ 7] += hk * w1.w;
            acc[ 8] += hk * w2.x;  acc[ 9] += hk * w2.y;
            acc[10] += hk * w2.z;  acc[11] += hk * w2.w;
            acc[12] += hk * w3.x;  acc[13] += hk * w3.y;
            acc[14] += hk * w3.z;  acc[15] += hk * w3.w;
        }

        if (L < 2) {
            #pragma unroll
            for (int j = 0; j < 16; ++j) acc[j] = fmaxf(acc[j], 0.f);
            __syncthreads();   // all waves done READING h before overwrite
            #pragma unroll
            for (int j = 0; j < 16; ++j) h[(dofs + j) * 64 + lane] = acc[j];
        }
    }

    float* o = out + gr * DD + dofs;
    #pragma unroll
    for (int j4 = 0; j4 < 4; ++j4) {
        float4 v = make_float4(acc[4*j4], acc[4*j4+1], acc[4*j4+2], acc[4*j4+3]);
        *reinterpret_cast<float4*>(o + 4 * j4) = v;
    }
}

// ---------------------------------------------------------------------------
// Kernel 2: per-(m, chunk) raw sums  csum[m][c][ch][d] = sum_{j in ch} K_j[d]*V_j[c]
// ---------------------------------------------------------------------------
__global__ __launch_bounds__(64) void chunksum_kernel(
    const float* __restrict__ x1, const float* __restrict__ x2,
    const float* __restrict__ x3, const float* __restrict__ x4,
    float* __restrict__ ws)
{
    const int m  = blockIdx.x >> 6;
    const int ch = blockIdx.x & 63;
    const int d  = threadIdx.x;
    const float* xm = (m == 0) ? x1 : (m == 1) ? x2 : (m == 2) ? x3 : x4;
    const float* K = ws + K_OFF + m * TT * DD;

    float s0 = 0.f, s1 = 0.f;
    #pragma unroll 4
    for (int j = ch * CS; j < ch * CS + CS; ++j) {
        const float kv = K[j * DD + d];
        s0 += kv * xm[j * DD + 0];
        s1 += kv * xm[j * DD + 1];
    }
    float* csum = ws + CSUM_OFF;
    csum[((m * 2 + 0) * NCH + ch) * DD + d] = s0;
    csum[((m * 2 + 1) * NCH + ch) * DD + d] = s1;
}

// ---------------------------------------------------------------------------
// Kernel 3: materialize inclusive prefix Z[m][c][j][d].  Each block folds its
// own exclusive chunk-prefix from the raw csums (same FP order as a scan).
// ---------------------------------------------------------------------------
__global__ __launch_bounds__(64) void zfill_kernel(
    const float* __restrict__ x1, const float* __restrict__ x2,
    const float* __restrict__ x3, const float* __restrict__ x4,
    float* __restrict__ ws)
{
    const int m  = blockIdx.x >> 6;
    const int ch = blockIdx.x & 63;
    const int d  = threadIdx.x;
    const float* xm = (m == 0) ? x1 : (m == 1) ? x2 : (m == 2) ? x3 : x4;
    const float* K = ws + K_OFF + m * TT * DD;
    const float* csum = ws + CSUM_OFF;
    float* Z = ws + Z_OFF;

    float r0 = 0.f, r1 = 0.f;
    for (int c = 0; c < NCH; ++c) {
        if (c < ch) {
            r0 += csum[((m * 2 + 0) * NCH + c) * DD + d];
            r1 += csum[((m * 2 + 1) * NCH + c) * DD + d];
        }
    }
    #pragma unroll 4
    for (int j = ch * CS; j < ch * CS + CS; ++j) {
        const float kv = K[j * DD + d];
        r0 += kv * xm[j * DD + 0];
        r1 += kv * xm[j * DD + 1];
        Z[((m * 2 + 0) * TT + j) * DD + d] = r0;
        Z[((m * 2 + 1) * TT + j) * DD + d] = r1;
    }
}

// ---------------------------------------------------------------------------
// Kernel 4: wave-per-row output.  p = upper_bound(t2_m, t1_i); out = Q_i . Z[p-1]
// ---------------------------------------------------------------------------
__global__ __launch_bounds__(256) void gather_kernel(
    const float* __restrict__ x1, const float* __restrict__ x2,
    const float* __restrict__ x3, const float* __restrict__ x4,
    const float* __restrict__ ws, float* __restrict__ out)
{
    const int lane = threadIdx.x & 63;
    const int wid  = threadIdx.x >> 6;
    const int i = blockIdx.x * 4 + wid;

    const float* Q = ws + Q_OFF;
    const float* Z = ws + Z_OFF;

    const float t1i = x1[i * DD + (DD - 1)];
    const float qd  = Q[i * DD + lane];
    float a0 = 0.f, a1 = 0.f;

    #pragma unroll
    for (int m = 0; m < 4; ++m) {
        const float* xm = (m == 0) ? x1 : (m == 1) ? x2 : (m == 2) ? x3 : x4;
        int lo = 0, hi = TT;
        while (lo < hi) {                       // upper_bound on sorted t2
            const int mid = (lo + hi) >> 1;
            if (xm[mid * DD + (DD - 1)] <= t1i) lo = mid + 1; else hi = mid;
        }
        if (lo > 0) {
            const int p = lo - 1;
            a0 += qd * Z[((m * 2 + 0) * TT + p) * DD + lane];
            a1 += qd * Z[((m * 2 + 1) * TT + p) * DD + lane];
        }
    }

    #pragma unroll
    for (int off = 32; off > 0; off >>= 1) {
        a0 += __shfl_xor(a0, off);
        a1 += __shfl_xor(a1, off);
    }
    if (lane == 0) {
        out[i * 2 + 0] = a0;
        out[i * 2 + 1] = a1;
    }
}

extern "C" void kernel_launch(void* const* d_in, const int* in_sizes, int n_in,
                              void* d_out, int out_size, void* d_ws, size_t ws_size,
                              hipStream_t stream)
{
    const float* x1   = (const float*)d_in[0];
    const float* x2   = (const float*)d_in[1];
    const float* x3   = (const float*)d_in[2];
    const float* x4   = (const float*)d_in[3];
    const float* Wq_w = (const float*)d_in[4];
    const float* Wq_b = (const float*)d_in[5];
    const float* Wk_w = (const float*)d_in[6];
    const float* Wk_b = (const float*)d_in[7];
    float* out = (float*)d_out;
    float* ws  = (float*)d_ws;

    hipLaunchKernelGGL(mlp_kernel,      dim3(5 * 64), dim3(256), 0, stream,
                       x1, x2, x3, x4, Wq_w, Wq_b, Wk_w, Wk_b, ws);
    hipLaunchKernelGGL(chunksum_kernel, dim3(4 * NCH), dim3(64), 0, stream,
                       x1, x2, x3, x4, ws);
    hipLaunchKernelGGL(zfill_kernel,    dim3(4 * NCH), dim3(64), 0, stream,
                       x1, x2, x3, x4, ws);
    hipLaunchKernelGGL(gather_kernel,   dim3(TT / 4), dim3(256), 0, stream,
                       x1, x2, x3, x4, ws, out);
}

// Round 3
// 47.265 us; speedup vs baseline: 1.5487x; 1.3927x over previous
//
#include <hip/hip_runtime.h>

#define TT 4096
#define DD 64
#define NCH 64
#define CS 64   // TT / NCH

// ws layout (in floats)
#define Q_OFF    0
#define K_OFF    (TT*DD)                  // 262144
#define Z_OFF    (K_OFF + 4*TT*DD)        // 1310720
#define CSUM_OFF (Z_OFF + 8*TT*DD)        // 3407872  (4*2*NCH*DD = 32768)
#define T_OFF    (CSUM_OFF + 8*NCH*DD)    // 3440640  (4*TT = 16384)  ~13.8 MB total

// ---------------------------------------------------------------------------
// Kernel 1: the five MLPs. Block = 1024 threads (16 waves) over a 64-row tile;
// wave w owns output dims [4w, 4w+4) (acc[4] -> low VGPR, 20 waves/CU).
// Tile load is fully coalesced (1 float4/thread) into transposed padded LDS
// h[k*65+row] (2-way bank aliasing = free). Weight loads are wave-uniform
// (readfirstlane'd dof) -> scalar/broadcast loads, pipelined by unroll 8.
// t-values (x[:,63]) are extracted for free during the tile load.
// ---------------------------------------------------------------------------
__global__ __launch_bounds__(1024) void mlp_kernel(
    const float* __restrict__ x1, const float* __restrict__ x2,
    const float* __restrict__ x3, const float* __restrict__ x4,
    const float* __restrict__ Wq_w, const float* __restrict__ Wq_b,
    const float* __restrict__ Wk_w, const float* __restrict__ Wk_b,
    float* __restrict__ ws)
{
    const int q    = blockIdx.x >> 6;    // 0 = Q-mlp, 1..4 = K-mlp (m = q-1)
    const int br   = blockIdx.x & 63;    // row block
    const int lane = threadIdx.x & 63;
    const int w    = threadIdx.x >> 6;   // 0..15

    const float* x; const float* W; const float* B; float* out;
    if (q == 0) { x = x1; W = Wq_w; B = Wq_b; out = ws + Q_OFF; }
    else {
        const int m = q - 1;
        x = (m == 0) ? x1 : (m == 1) ? x2 : (m == 2) ? x3 : x4;
        W = Wk_w + m * 3 * DD * DD;
        B = Wk_b + m * 3 * DD;
        out = ws + K_OFF + m * TT * DD;
    }

    __shared__ float h[DD * 65];   // h[k*65 + row], padded

    // coalesced tile load: 64 rows x 64 dims = 4096 floats = 1024 float4
    {
        const float4 v = reinterpret_cast<const float4*>(x + br * 64 * DD)[threadIdx.x];
        const int e   = threadIdx.x * 4;
        const int row = e >> 6;
        const int k0  = e & 63;
        h[(k0 + 0) * 65 + row] = v.x;
        h[(k0 + 1) * 65 + row] = v.y;
        h[(k0 + 2) * 65 + row] = v.z;
        h[(k0 + 3) * 65 + row] = v.w;
        if (q >= 1 && k0 == 60) {               // free t-extraction (x[:,63])
            ws[T_OFF + (q - 1) * TT + br * 64 + row] = v.w;
        }
    }

    const int dofs = __builtin_amdgcn_readfirstlane(4 * w);

    float a0, a1, a2, a3;
    for (int L = 0; L < 3; ++L) {
        __syncthreads();
        const float* WL = W + L * DD * DD + dofs;
        const float* BL = B + L * DD + dofs;
        a0 = BL[0]; a1 = BL[1]; a2 = BL[2]; a3 = BL[3];

        #pragma unroll 8
        for (int k = 0; k < DD; ++k) {
            const float hk = h[k * 65 + lane];
            const float4 wv = *reinterpret_cast<const float4*>(WL + k * DD);
            a0 += hk * wv.x; a1 += hk * wv.y; a2 += hk * wv.z; a3 += hk * wv.w;
        }

        if (L < 2) {
            a0 = fmaxf(a0, 0.f); a1 = fmaxf(a1, 0.f);
            a2 = fmaxf(a2, 0.f); a3 = fmaxf(a3, 0.f);
            __syncthreads();
            h[(dofs + 0) * 65 + lane] = a0;
            h[(dofs + 1) * 65 + lane] = a1;
            h[(dofs + 2) * 65 + lane] = a2;
            h[(dofs + 3) * 65 + lane] = a3;
        }
    }

    float* o = out + (br * 64 + lane) * DD + dofs;
    *reinterpret_cast<float4*>(o) = make_float4(a0, a1, a2, a3);
}

// ---------------------------------------------------------------------------
// Kernel 2: chunk sums  csum[mc][ch][d] = sum_{j in ch} K_j[d]*V_j[c].
// Block = 256 threads (4 waves); wave w sums 16 rows; LDS tree-reduce.
// ---------------------------------------------------------------------------
__global__ __launch_bounds__(256) void chunksum_kernel(
    const float* __restrict__ x1, const float* __restrict__ x2,
    const float* __restrict__ x3, const float* __restrict__ x4,
    float* __restrict__ ws)
{
    const int m  = blockIdx.x >> 6;
    const int ch = blockIdx.x & 63;
    const int d  = threadIdx.x & 63;
    const int w  = threadIdx.x >> 6;
    const float* xm = (m == 0) ? x1 : (m == 1) ? x2 : (m == 2) ? x3 : x4;
    const float* K = ws + K_OFF + m * TT * DD;

    float s0 = 0.f, s1 = 0.f;
    const int j0 = ch * CS + w * 16;
    #pragma unroll
    for (int jj = 0; jj < 16; ++jj) {
        const int j = j0 + jj;
        const float kv = K[j * DD + d];
        s0 += kv * xm[j * DD + 0];
        s1 += kv * xm[j * DD + 1];
    }

    __shared__ float p0[4][64], p1[4][64];
    p0[w][d] = s0; p1[w][d] = s1;
    __syncthreads();
    if (w == 0) {
        float* csum = ws + CSUM_OFF;
        const float r0 = p0[0][d] + p0[1][d] + p0[2][d] + p0[3][d];
        const float r1 = p1[0][d] + p1[1][d] + p1[2][d] + p1[3][d];
        csum[((m * 2 + 0) * NCH + ch) * DD + d] = r0;
        csum[((m * 2 + 1) * NCH + ch) * DD + d] = r1;
    }
}

// ---------------------------------------------------------------------------
// Kernel 3: inclusive prefix Z[mc][j][d]. One wave per (m,c,ch). Chunk-prefix
// fold uses UNCONDITIONAL loads + select so all 63 loads pipeline in one
// latency burst; main loop unrolled so K loads prefetch ahead of the FMA chain.
// ---------------------------------------------------------------------------
__global__ __launch_bounds__(64) void zfill_kernel(
    const float* __restrict__ x1, const float* __restrict__ x2,
    const float* __restrict__ x3, const float* __restrict__ x4,
    float* __restrict__ ws)
{
    const int mc = blockIdx.x >> 6;    // m*2 + c
    const int ch = blockIdx.x & 63;
    const int m  = mc >> 1;
    const int c  = mc & 1;
    const int d  = threadIdx.x;
    const float* xm = (m == 0) ? x1 : (m == 1) ? x2 : (m == 2) ? x3 : x4;
    const float* K = ws + K_OFF + m * TT * DD;
    const float* csum = ws + CSUM_OFF + mc * NCH * DD;
    float* Z = ws + Z_OFF + mc * TT * DD;

    float r = 0.f;
    #pragma unroll
    for (int cc = 0; cc < NCH - 1; ++cc) {
        const float v = csum[cc * DD + d];
        r += (cc < ch) ? v : 0.f;
    }

    const int j0 = ch * CS;
    #pragma unroll 8
    for (int jj = 0; jj < CS; ++jj) {
        const int j = j0 + jj;
        r += K[j * DD + d] * xm[j * DD + c];
        Z[j * DD + d] = r;
    }
}

// ---------------------------------------------------------------------------
// Kernel 4: wave-per-row output. The 4 binary searches (independent chains)
// run INTERLEAVED against dense t-arrays (16 KB each, L1/L2-resident), then
// out_i = Q_i . Z[p-1] with a 64-lane shuffle reduce.
// ---------------------------------------------------------------------------
__global__ __launch_bounds__(256) void gather_kernel(
    const float* __restrict__ ws, float* __restrict__ out)
{
    const int lane = threadIdx.x & 63;
    const int wid  = threadIdx.x >> 6;
    const int i = blockIdx.x * 4 + wid;

    const float* Q  = ws + Q_OFF;
    const float* Z  = ws + Z_OFF;
    const float* tb = ws + T_OFF;

    const float t1i = tb[0 * TT + i];        // t1 = x1's times
    const float qd  = Q[i * DD + lane];

    int lo[4] = {0, 0, 0, 0};
    int hi[4] = {TT, TT, TT, TT};
    #pragma unroll
    for (int s = 0; s < 13; ++s) {
        #pragma unroll
        for (int m = 0; m < 4; ++m) {
            if (lo[m] < hi[m]) {
                const int mid = (lo[m] + hi[m]) >> 1;
                const bool le = tb[m * TT + mid] <= t1i;
                lo[m] = le ? mid + 1 : lo[m];
                hi[m] = le ? hi[m] : mid;
            }
        }
    }

    float a0 = 0.f, a1 = 0.f;
    #pragma unroll
    for (int m = 0; m < 4; ++m) {
        if (lo[m] > 0) {
            const int p = lo[m] - 1;
            a0 += qd * Z[((m * 2 + 0) * TT + p) * DD + lane];
            a1 += qd * Z[((m * 2 + 1) * TT + p) * DD + lane];
        }
    }

    #pragma unroll
    for (int off = 32; off > 0; off >>= 1) {
        a0 += __shfl_xor(a0, off);
        a1 += __shfl_xor(a1, off);
    }
    if (lane == 0) {
        out[i * 2 + 0] = a0;
        out[i * 2 + 1] = a1;
    }
}

extern "C" void kernel_launch(void* const* d_in, const int* in_sizes, int n_in,
                              void* d_out, int out_size, void* d_ws, size_t ws_size,
                              hipStream_t stream)
{
    const float* x1   = (const float*)d_in[0];
    const float* x2   = (const float*)d_in[1];
    const float* x3   = (const float*)d_in[2];
    const float* x4   = (const float*)d_in[3];
    const float* Wq_w = (const float*)d_in[4];
    const float* Wq_b = (const float*)d_in[5];
    const float* Wk_w = (const float*)d_in[6];
    const float* Wk_b = (const float*)d_in[7];
    float* out = (float*)d_out;
    float* ws  = (float*)d_ws;

    hipLaunchKernelGGL(mlp_kernel,      dim3(5 * 64), dim3(1024), 0, stream,
                       x1, x2, x3, x4, Wq_w, Wq_b, Wk_w, Wk_b, ws);
    hipLaunchKernelGGL(chunksum_kernel, dim3(4 * NCH), dim3(256), 0, stream,
                       x1, x2, x3, x4, ws);
    hipLaunchKernelGGL(zfill_kernel,    dim3(8 * NCH), dim3(64), 0, stream,
                       x1, x2, x3, x4, ws);
    hipLaunchKernelGGL(gather_kernel,   dim3(TT / 4), dim3(256), 0, stream,
                       ws, out);
}